// Round 1
// baseline (4223.275 us; speedup 1.0000x reference)
//
#include <hip/hip_runtime.h>
#include <math.h>

#define B_    2
#define N_    4096
#define BN_   (B_*N_)
#define H0    480
#define W0    640
#define FH_   240
#define FW_   320
#define PIX_  (B_*FH_*FW_)     // 153600
#define KNN_K 20
#define CH_   16               // candidate chunks per KNN
#define CHSZ  (N_/CH_)         // 256

// ---------------- workspace layout (float offsets) ----------------
static const size_t OFF_RS   = 0;                       // 2880
static const size_t OFF_CS   = 2944;                    // 3840
static const size_t OFF_PH   = 6784;                    // 23040
static const size_t OFF_PW   = 29824;                   // 30720
static const size_t OFF_Y8   = 60544;                   // 17920
static const size_t OFF_AH   = 78464;                   // 23040
static const size_t OFF_AW   = 101504;                  // 30720
static const size_t OFF_VB   = 132224;                  // 8192 (int)
static const size_t OFF_UB   = 140416;                  // 8192 (int)
static const size_t OFF_F3D  = 148608;                  // 262144
static const size_t OFF_XX   = 410752;                  // 8192
static const size_t OFF_PV   = 418944;                  // 2621440
static const size_t OFF_PI   = 3040384;                 // 2621440 (int)
static const size_t OFF_IDX  = 5661824;                 // 163840 (int)
static const size_t OFF_X1   = 5825664;                 // 524288
static const size_t OFF_X2   = 6349952;                 // 524288
static const size_t OFF_X3   = 6874240;                 // 1048576
static const size_t OFF_T1   = 7922816;                 // 4096
static const size_t OFF_T2   = 7926912;                 // 8192
static const size_t OFF_T3   = 7935104;                 // 16384
static const size_t OFF_T7A  = 7951488;                 // 4096
static const size_t OFF_T7B  = 7955584;                 // 8192
static const size_t OFF_FMA  = 7963776;                 // 9830400
static const size_t OFF_FMV  = 17794176;                // 9830400
static const size_t OFF_FMB  = 27624576;                // 9830400

// ---------------- small weight transposes ----------------
__global__ void k_transpose(const float* __restrict__ w1, const float* __restrict__ w2,
                            const float* __restrict__ w3, const float* __restrict__ w7a,
                            const float* __restrict__ w7b,
                            float* __restrict__ t1, float* __restrict__ t2,
                            float* __restrict__ t3, float* __restrict__ t7a,
                            float* __restrict__ t7b) {
    int t = blockIdx.x * 256 + threadIdx.x;
    if (t < 4096) {                         // conv1 (64,64) -> [i*64+o]
        int i = t >> 6, o = t & 63; t1[i*64+o] = w1[o*64+i];
    } else if (t < 12288) {                 // conv2 (64,128) -> [i*64+o], i<128
        int r = t - 4096; int i = r >> 6, o = r & 63; t2[i*64+o] = w2[o*128+i];
    } else if (t < 28672) {                 // conv3 (128,128) -> [i*128+o]
        int r = t - 12288; int i = r >> 7, o = r & 127; t3[i*128+o] = w3[o*128+i];
    } else if (t < 32768) {                 // conv7a (64,64) -> [c*64+o]
        int r = t - 28672; int c = r >> 6, o = r & 63; t7a[c*64+o] = w7a[o*64+c];
    } else if (t < 40960) {                 // conv7b (128,64) -> [o*128+p]
        int r = t - 32768; int o = r >> 7, p = r & 127; t7b[o*128+p] = w7b[p*64+o];
    }
}

// ---------------- input row/col sums ----------------
__global__ void k_colsum(const float* __restrict__ img, float* __restrict__ cs) {
    int bc = blockIdx.x; int x = threadIdx.x;   // grid 6, block 640
    const float* p = img + (size_t)bc * H0 * W0;
    float acc = 0.f;
    for (int h = 0; h < H0; ++h) acc += p[h * W0 + x];
    cs[bc * W0 + x] = acc;
}
__global__ void k_rowsum(const float* __restrict__ img, float* __restrict__ rs) {
    int bc = blockIdx.x; int y = threadIdx.x;   // grid 6, block 480
    const float* p = img + (size_t)bc * H0 * W0 + (size_t)y * W0;
    float acc = 0.f;
    for (int x = 0; x < W0; ++x) acc += p[x];
    rs[bc * H0 + y] = acc;
}

// ---------------- pooled conv means ph/pw ----------------
__global__ void k_ph(const float* __restrict__ img, const float* __restrict__ rs,
                     const float* __restrict__ w, const float* __restrict__ bias,
                     float* __restrict__ ph) {
    int t = blockIdx.x * 256 + threadIdx.x;
    if (t >= B_ * 24 * H0) return;
    int h = t % H0; int bc = t / H0; int c = bc % 24; int b = bc / 24;
    float acc = 0.f;
    for (int ic = 0; ic < 3; ++ic)
        for (int dy = 0; dy < 3; ++dy) {
            int y = h + dy - 1;
            if ((unsigned)y >= (unsigned)H0) continue;
            float r = rs[(b*3+ic)*H0 + y];
            const float* row = img + (size_t)((b*3+ic)*H0 + y) * W0;
            float e0 = row[0], eL = row[W0-1];
            const float* wp = w + ((c*3+ic)*3+dy)*3;
            acc += wp[0]*(r - eL) + wp[1]*r + wp[2]*(r - e0);
        }
    ph[t] = bias[c] + acc / 640.0f;
}
__global__ void k_pw(const float* __restrict__ img, const float* __restrict__ cs,
                     const float* __restrict__ w, const float* __restrict__ bias,
                     float* __restrict__ pw) {
    int t = blockIdx.x * 256 + threadIdx.x;
    if (t >= B_ * 24 * W0) return;
    int x = t % W0; int bc = t / W0; int c = bc % 24; int b = bc / 24;
    float acc = 0.f;
    for (int ic = 0; ic < 3; ++ic)
        for (int dx = 0; dx < 3; ++dx) {
            int xx = x + dx - 1;
            if ((unsigned)xx >= (unsigned)W0) continue;
            float csv = cs[(b*3+ic)*W0 + xx];
            const float* base = img + (size_t)(b*3+ic) * H0 * W0;
            float top = base[xx];                   // h=0
            float bot = base[(size_t)(H0-1)*W0 + xx];
            const float* wp = w + ((c*3+ic)*3)*3 + dx;
            acc += wp[0]*(csv - bot) + wp[3]*csv + wp[6]*(csv - top);
        }
    pw[t] = bias[c] + acc / 480.0f;
}

// ---------------- coord-attention mid + gates ----------------
__global__ void k_y8(const float* __restrict__ ph, const float* __restrict__ pw,
                     const float* __restrict__ c1w, const float* __restrict__ c1b,
                     const float* __restrict__ bnp, float* __restrict__ y8) {
    int t = blockIdx.x * 256 + threadIdx.x;
    if (t >= B_ * 8 * 1120) return;
    int pos = t % 1120; int bj = t / 1120; int j = bj % 8; int b = bj / 8;
    float s = c1b[j];
    for (int c = 0; c < 24; ++c) {
        float yv = (pos < H0) ? ph[(b*24+c)*H0 + pos] : pw[(b*24+c)*W0 + (pos - H0)];
        s = fmaf(c1w[j*24+c], yv, s);
    }
    float g = bnp[j], be = bnp[8+j], m = bnp[16+j], va = bnp[24+j];
    float v = (s - m) * (g / sqrtf(va + 1e-5f)) + be;
    float hs = v * fminf(fmaxf(v + 3.f, 0.f), 6.f) * (1.f/6.f);
    y8[(b*8+j)*1120 + pos] = hs;
}
__global__ void k_ahw(const float* __restrict__ y8,
                      const float* __restrict__ chw, const float* __restrict__ chb,
                      const float* __restrict__ cww, const float* __restrict__ cwb,
                      float* __restrict__ ah, float* __restrict__ aw) {
    int t = blockIdx.x * 256 + threadIdx.x;
    if (t >= B_ * 24 * 1120) return;
    int pos = t % 1120; int bc = t / 1120; int c = bc % 24; int b = bc / 24;
    if (pos < H0) {
        float s = chb[c];
        for (int j = 0; j < 8; ++j) s = fmaf(chw[c*8+j], y8[(b*8+j)*1120 + pos], s);
        ah[(b*24+c)*H0 + pos] = 1.f / (1.f + expf(-s));
    } else {
        float s = cwb[c];
        for (int j = 0; j < 8; ++j) s = fmaf(cww[c*8+j], y8[(b*8+j)*1120 + pos], s);
        aw[(b*24+c)*W0 + (pos - H0)] = 1.f / (1.f + expf(-s));
    }
}

// ---------------- feat3d gather (+v/u + idx output) ----------------
__global__ void k_feat3d(const float* __restrict__ pc, const float* __restrict__ img,
                         const float* __restrict__ w, const float* __restrict__ bias,
                         const float* __restrict__ ah, const float* __restrict__ aw,
                         float* __restrict__ f3d, int* __restrict__ vbuf,
                         int* __restrict__ ubuf, float* __restrict__ idx_out) {
    int t = blockIdx.x * 256 + threadIdx.x;
    if (t >= BN_ * 32) return;
    int c = t & 31; int bn = t >> 5; int b = bn >> 12; int n = bn & (N_-1);
    float pv = pc[(b*8 + 0)*N_ + n];
    float pu = pc[(b*8 + 1)*N_ + n];
    int v = (int)floorf(pv + 240.f);
    int u = (int)floorf(pu + 320.f);
    float f;
    if (c < 8) {
        f = pc[(b*8 + c)*N_ + n];
    } else {
        int co = c - 8;
        float acc = bias[co];
        for (int ic = 0; ic < 3; ++ic)
            for (int dy = 0; dy < 3; ++dy) {
                int y = v + dy - 1;
                if ((unsigned)y >= (unsigned)H0) continue;
                for (int dx = 0; dx < 3; ++dx) {
                    int x = u + dx - 1;
                    if ((unsigned)x >= (unsigned)W0) continue;
                    acc = fmaf(w[((co*3+ic)*3+dy)*3+dx],
                               img[((size_t)(b*3+ic)*H0 + y)*W0 + x], acc);
                }
            }
        f = acc * ah[(b*24+co)*H0 + v] * aw[(b*24+co)*W0 + u];
    }
    f3d[(size_t)bn*32 + c] = f;
    if (c == 0) {
        vbuf[bn] = v; ubuf[bn] = u;
        idx_out[bn] = (float)b;
        idx_out[BN_ + bn] = (float)(v >> 1);
        idx_out[2*BN_ + bn] = (float)(u >> 1);
    }
}

// ---------------- squared norms ----------------
template<int C>
__global__ void k_sqnorm(const float* __restrict__ X, float* __restrict__ XX) {
    int t = blockIdx.x * 256 + threadIdx.x;
    if (t >= BN_) return;
    float acc = 0.f;
    const float* p = X + (size_t)t * C;
#pragma unroll
    for (int i = 0; i < C; ++i) acc = fmaf(p[i], p[i], acc);
    XX[t] = acc;
}

// ---------------- KNN: chunked partial top-20 ----------------
template<int C>
__launch_bounds__(256)
__global__ void knn_partial(const float* __restrict__ X, const float* __restrict__ XX,
                            float* __restrict__ pV, int* __restrict__ pI) {
    // grid: B_ * (N_/256) * CH_ blocks, 256 threads
    int bid = blockIdx.x;
    int ch = bid & (CH_-1); int rem = bid / CH_;
    int qt = rem & 15; int b = rem >> 4;
    int q = qt * 256 + threadIdx.x;
    int row = b * N_ + q;
    float qv[C];
#pragma unroll
    for (int i = 0; i < C; ++i) qv[i] = X[(size_t)row * C + i];
    float xxq = XX[row];
    float val[KNN_K]; int idx[KNN_K];
#pragma unroll
    for (int j = 0; j < KNN_K; ++j) { val[j] = -INFINITY; idx[j] = -1; }
    __shared__ float cf[128 * C + 128];
    float* cxx = cf + 128 * C;
    int cbase = ch * CHSZ;
    for (int t = 0; t < CHSZ / 128; ++t) {
        __syncthreads();
        int tb = cbase + t * 128;
        for (int j = threadIdx.x; j < 128 * C; j += 256) {
            int r = j / C, col = j % C;
            cf[j] = X[((size_t)b * N_ + tb + r) * C + col];
        }
        if (threadIdx.x < 128) cxx[threadIdx.x] = XX[b * N_ + tb + threadIdx.x];
        __syncthreads();
        for (int m = 0; m < 128; ++m) {
            float dot = 0.f;
#pragma unroll
            for (int i = 0; i < C; ++i) dot = fmaf(qv[i], cf[m * C + i], dot);
            float pd = 2.f * dot - xxq - cxx[m];
            if (pd > val[KNN_K-1]) {
                float cv = pd; int ci = tb + m; bool ins = false;
#pragma unroll
                for (int j = 0; j < KNN_K; ++j) {
                    bool sw = ins || (cv > val[j]);
                    if (sw) {
                        float tv = val[j]; val[j] = cv; cv = tv;
                        int ti = idx[j]; idx[j] = ci; ci = ti;
                        ins = true;
                    }
                }
            }
        }
    }
    size_t base = ((size_t)row * CH_ + ch) * KNN_K;
#pragma unroll
    for (int j = 0; j < KNN_K; ++j) { pV[base + j] = val[j]; pI[base + j] = idx[j]; }
}

__global__ void k_merge(const float* __restrict__ pV, const int* __restrict__ pI,
                        int* __restrict__ idxb) {
    int t = blockIdx.x * 256 + threadIdx.x;   // grid 32
    __shared__ int sh[CH_ * 256];
    for (int ch = 0; ch < CH_; ++ch) sh[ch*256 + threadIdx.x] = 0;
    size_t base = (size_t)t * CH_ * KNN_K;
    for (int slot = 0; slot < KNN_K; ++slot) {
        float best = -INFINITY; int bc = 0;
        for (int ch = 0; ch < CH_; ++ch) {
            int hd = sh[ch*256 + threadIdx.x];
            if (hd < KNN_K) {
                float v = pV[base + (size_t)ch*KNN_K + hd];
                if (v > best) { best = v; bc = ch; }
            }
        }
        int hd = sh[bc*256 + threadIdx.x];
        sh[bc*256 + threadIdx.x] = hd + 1;
        idxb[(size_t)t * KNN_K + slot] = pI[base + (size_t)bc*KNN_K + hd];
    }
}

// ---------------- EdgeConv: gather + 1x1 conv + bn + lrelu + max_k ----------------
template<int CIN, int COUT, int P>   // P*COUT == 256
__launch_bounds__(256)
__global__ void edgeconv(const float* __restrict__ X, const int* __restrict__ idxb,
                         const float* __restrict__ wT, const float* __restrict__ bnp,
                         float* __restrict__ Y) {
    __shared__ float sctr[P][CIN];
    __shared__ float snb[P][KNN_K * CIN];
    int base = blockIdx.x * P;
    int tid = threadIdx.x;
    for (int j = tid; j < P * CIN; j += 256) {
        int p = j / CIN, i = j % CIN;
        sctr[p][i] = X[(size_t)(base + p) * CIN + i];
    }
    for (int j = tid; j < P * KNN_K * CIN; j += 256) {
        int p = j / (KNN_K * CIN); int r = j % (KNN_K * CIN);
        int k = r / CIN; int i = r % CIN;
        int b = (base + p) / N_;
        int ni = idxb[(size_t)(base + p) * KNN_K + k];
        snb[p][k * CIN + i] = X[((size_t)b * N_ + ni) * CIN + i];
    }
    __syncthreads();
    int p = tid / COUT, o = tid % COUT;
    float g = bnp[o], bb = bnp[COUT + o], m = bnp[2*COUT + o], va = bnp[3*COUT + o];
    float a = g / sqrtf(va + 1e-5f);
    float sh = bb - m * a;
    float accc = 0.f;
#pragma unroll
    for (int i = 0; i < CIN; ++i)
        accc = fmaf(wT[(CIN + i) * COUT + o] - wT[i * COUT + o], sctr[p][i], accc);
    float mx = -INFINITY;
    for (int k = 0; k < KNN_K; ++k) {
        float s = accc;
#pragma unroll
        for (int i = 0; i < CIN; ++i)
            s = fmaf(wT[i * COUT + o], snb[p][k * CIN + i], s);
        float r = fmaf(s, a, sh);
        r = (r >= 0.f) ? r : 0.2f * r;
        mx = fmaxf(mx, r);
    }
    Y[(size_t)(base + p) * COUT + o] = mx;
}

// ---------------- lin4 (256->256->64) + scatter-add ----------------
__launch_bounds__(256)
__global__ void k_lin4(const float* __restrict__ x1, const float* __restrict__ x2,
                       const float* __restrict__ x3, const float* __restrict__ l4a,
                       const float* __restrict__ l4b, const int* __restrict__ vbuf,
                       const int* __restrict__ ubuf, float* __restrict__ fmA) {
    int bn = blockIdx.x; int tid = threadIdx.x;
    __shared__ float xc[256]; __shared__ float t1[256];
    if (tid < 64)        xc[tid] = x1[(size_t)bn*64 + tid];
    else if (tid < 128)  xc[tid] = x2[(size_t)bn*64 + tid - 64];
    else                 xc[tid] = x3[(size_t)bn*128 + tid - 128];
    __syncthreads();
    float acc = 0.f;
    for (int i = 0; i < 256; ++i) acc = fmaf(xc[i], l4a[i*256 + tid], acc);
    t1[tid] = acc;
    __syncthreads();
    if (tid < 64) {
        float a2 = 0.f;
        for (int i = 0; i < 256; ++i) a2 = fmaf(t1[i], l4b[i*64 + tid], a2);
        int b = bn >> 12; int v = vbuf[bn] >> 1; int u = ubuf[bn] >> 1;
        atomicAdd(fmA + ((size_t)(b*FH_ + v)*FW_ + u)*64 + tid, a2);
    }
}

// ---------------- per-pixel channel softmax ----------------
__global__ void k_softmax(float* __restrict__ fm) {
    int pix = blockIdx.x * 4 + (threadIdx.x >> 6);
    int l = threadIdx.x & 63;
    float x = fm[(size_t)pix*64 + l];
    float m = x;
    for (int off = 32; off > 0; off >>= 1) m = fmaxf(m, __shfl_xor(m, off));
    float e = expf(x - m);
    float s = e;
    for (int off = 32; off > 0; off >>= 1) s += __shfl_xor(s, off);
    fm[(size_t)pix*64 + l] = e / s;
}

// ---------------- DCN value GEMV ----------------
__global__ void k_dcnval(const float* __restrict__ in, const float* __restrict__ vw,
                         const float* __restrict__ vb, float* __restrict__ val) {
    __shared__ float sx[256];
    int tid = threadIdx.x;
    size_t base = (size_t)blockIdx.x * 256;
    sx[tid] = in[base + tid];
    __syncthreads();
    int o = tid & 63; int grp = tid >> 6;
    const float* xr = sx + grp*64;
    float acc = vb[o];
    for (int i = 0; i < 64; ++i) acc = fmaf(xr[i], vw[i*64 + o], acc);
    val[base + tid] = acc;
}

// ---------------- DCN offsets + sampling + out-proj + bn + lrelu ----------------
__launch_bounds__(128)
__global__ void k_dcnsamp(const float* __restrict__ in, const float* __restrict__ val,
                          const float* __restrict__ ow, const float* __restrict__ ob,
                          const float* __restrict__ pwm, const float* __restrict__ pbm,
                          const float* __restrict__ bnp, float* __restrict__ out) {
    int pix = blockIdx.x; int tid = threadIdx.x;
    int b = pix / (FH_*FW_); int hw = pix % (FH_*FW_);
    int h = hw / FW_; int w = hw % FW_;
    __shared__ float sx[64]; __shared__ float som[108]; __shared__ float ss[64];
    if (tid < 64) sx[tid] = in[(size_t)pix*64 + tid];
    __syncthreads();
    if (tid < 108) {
        float a = ob[tid];
        for (int i = 0; i < 64; ++i) a = fmaf(sx[i], ow[i*108 + tid], a);
        som[tid] = a;
    }
    __syncthreads();
    if (tid < 64) {
        int g = tid >> 4;
        const float* vbase = val + (size_t)b * FH_ * FW_ * 64 + tid;
        float acc = 0.f;
        for (int k = 0; k < 9; ++k) {
            int kx = k % 3 - 1, ky = k / 3 - 1;
            float lx = (float)(w + kx) + som[g*27 + k*3 + 0];
            float ly = (float)(h + ky) + som[g*27 + k*3 + 1];
            float msk = som[g*27 + k*3 + 2];
            float x0f = floorf(lx), y0f = floorf(ly);
            float wx = lx - x0f, wy = ly - y0f;
            int x0 = (int)x0f, y0 = (int)y0f;
            float w00 = (1.f-wx)*(1.f-wy), w01 = wx*(1.f-wy);
            float w10 = (1.f-wx)*wy,       w11 = wx*wy;
            if ((unsigned)y0 < (unsigned)FH_ && (unsigned)x0 < (unsigned)FW_)
                acc = fmaf(msk*w00, vbase[((size_t)y0*FW_ + x0)*64], acc);
            if ((unsigned)y0 < (unsigned)FH_ && (unsigned)(x0+1) < (unsigned)FW_)
                acc = fmaf(msk*w01, vbase[((size_t)y0*FW_ + x0+1)*64], acc);
            if ((unsigned)(y0+1) < (unsigned)FH_ && (unsigned)x0 < (unsigned)FW_)
                acc = fmaf(msk*w10, vbase[((size_t)(y0+1)*FW_ + x0)*64], acc);
            if ((unsigned)(y0+1) < (unsigned)FH_ && (unsigned)(x0+1) < (unsigned)FW_)
                acc = fmaf(msk*w11, vbase[((size_t)(y0+1)*FW_ + x0+1)*64], acc);
        }
        ss[tid] = acc;
    }
    __syncthreads();
    if (tid < 64) {
        float a = pbm[tid];
        for (int i = 0; i < 64; ++i) a = fmaf(ss[i], pwm[i*64 + tid], a);
        float g = bnp[tid], be = bnp[64+tid], m = bnp[128+tid], va = bnp[192+tid];
        float sc = g / sqrtf(va + 1e-5f);
        float r = (a - m) * sc + be;
        out[(size_t)pix*64 + tid] = (r >= 0.f) ? r : 0.2f * r;
    }
}

// ---------------- conv7a + conv7b ----------------
__launch_bounds__(128)
__global__ void k_conv7(const float* __restrict__ in, const float* __restrict__ w7aT,
                        const float* __restrict__ w7bT, float* __restrict__ out) {
    int pix = blockIdx.x; int tid = threadIdx.x;
    int b = pix / (FH_*FW_); int hw = pix % (FH_*FW_);
    __shared__ float sx[64]; __shared__ float st[64];
    if (tid < 64) sx[tid] = in[(size_t)pix*64 + tid];
    __syncthreads();
    if (tid < 64) {
        float a = 0.f;
        for (int c = 0; c < 64; ++c) a = fmaf(sx[c], w7aT[c*64 + tid], a);
        st[tid] = a;
    }
    __syncthreads();
    float a = 0.f;
    for (int o = 0; o < 64; ++o) a = fmaf(st[o], w7bT[o*128 + tid], a);
    out[((size_t)b*128 + tid)*(FH_*FW_) + hw] = a;
}

// ---------------- launch ----------------
extern "C" void kernel_launch(void* const* d_in, const int* in_sizes, int n_in,
                              void* d_out, int out_size, void* d_ws, size_t ws_size,
                              hipStream_t stream) {
    (void)in_sizes; (void)n_in; (void)out_size; (void)ws_size;
    const float* pc   = (const float*)d_in[0];
    const float* img  = (const float*)d_in[1];
    const float* pcw  = (const float*)d_in[2];
    const float* pcb  = (const float*)d_in[3];
    const float* c1w  = (const float*)d_in[4];
    const float* c1b  = (const float*)d_in[5];
    const float* cabn = (const float*)d_in[6];
    const float* chw  = (const float*)d_in[7];
    const float* chb  = (const float*)d_in[8];
    const float* cww  = (const float*)d_in[9];
    const float* cwb  = (const float*)d_in[10];
    const float* w1   = (const float*)d_in[11];
    const float* bn1  = (const float*)d_in[12];
    const float* w2   = (const float*)d_in[13];
    const float* bn2  = (const float*)d_in[14];
    const float* w3   = (const float*)d_in[15];
    const float* bn3  = (const float*)d_in[16];
    const float* l4a  = (const float*)d_in[17];
    const float* l4b  = (const float*)d_in[18];
    const float* d5ow = (const float*)d_in[19];
    const float* d5ob = (const float*)d_in[20];
    const float* d5vw = (const float*)d_in[21];
    const float* d5vb = (const float*)d_in[22];
    const float* d5pw = (const float*)d_in[23];
    const float* d5pb = (const float*)d_in[24];
    const float* bn5  = (const float*)d_in[25];
    const float* d6ow = (const float*)d_in[26];
    const float* d6ob = (const float*)d_in[27];
    const float* d6vw = (const float*)d_in[28];
    const float* d6vb = (const float*)d_in[29];
    const float* d6pw = (const float*)d_in[30];
    const float* d6pb = (const float*)d_in[31];
    const float* bn6  = (const float*)d_in[32];
    const float* w7a  = (const float*)d_in[33];
    const float* w7b  = (const float*)d_in[34];

    float* ws  = (float*)d_ws;
    float* out = (float*)d_out;

    float* rs  = ws + OFF_RS;   float* cs  = ws + OFF_CS;
    float* ph  = ws + OFF_PH;   float* pw  = ws + OFF_PW;
    float* y8  = ws + OFF_Y8;   float* ah  = ws + OFF_AH;  float* aw = ws + OFF_AW;
    int*   vb  = (int*)(ws + OFF_VB);
    int*   ub  = (int*)(ws + OFF_UB);
    float* f3d = ws + OFF_F3D;  float* xx  = ws + OFF_XX;
    float* pV  = ws + OFF_PV;
    int*   pI  = (int*)(ws + OFF_PI);
    int*   idxb = (int*)(ws + OFF_IDX);
    float* x1  = ws + OFF_X1;   float* x2  = ws + OFF_X2;  float* x3 = ws + OFF_X3;
    float* t1  = ws + OFF_T1;   float* t2  = ws + OFF_T2;  float* t3 = ws + OFF_T3;
    float* t7a = ws + OFF_T7A;  float* t7b = ws + OFF_T7B;
    float* fmA = ws + OFF_FMA;  float* fmV = ws + OFF_FMV; float* fmB = ws + OFF_FMB;

    hipMemsetAsync(fmA, 0, (size_t)PIX_ * 64 * sizeof(float), stream);

    k_transpose<<<160, 256, 0, stream>>>(w1, w2, w3, w7a, w7b, t1, t2, t3, t7a, t7b);
    k_colsum<<<B_*3, W0, 0, stream>>>(img, cs);
    k_rowsum<<<B_*3, H0, 0, stream>>>(img, rs);
    k_ph<<<(B_*24*H0 + 255)/256, 256, 0, stream>>>(img, rs, pcw, pcb, ph);
    k_pw<<<(B_*24*W0 + 255)/256, 256, 0, stream>>>(img, cs, pcw, pcb, pw);
    k_y8<<<(B_*8*1120 + 255)/256, 256, 0, stream>>>(ph, pw, c1w, c1b, cabn, y8);
    k_ahw<<<(B_*24*1120 + 255)/256, 256, 0, stream>>>(y8, chw, chb, cww, cwb, ah, aw);
    k_feat3d<<<(BN_*32)/256, 256, 0, stream>>>(pc, img, pcw, pcb, ah, aw, f3d, vb, ub,
                                               out + (size_t)B_*128*FH_*FW_);

    // EdgeConv stage 1
    k_sqnorm<32><<<BN_/256, 256, 0, stream>>>(f3d, xx);
    knn_partial<32><<<B_*16*CH_, 256, 0, stream>>>(f3d, xx, pV, pI);
    k_merge<<<BN_/256, 256, 0, stream>>>(pV, pI, idxb);
    edgeconv<32,64,4><<<BN_/4, 256, 0, stream>>>(f3d, idxb, t1, bn1, x1);
    // stage 2
    k_sqnorm<64><<<BN_/256, 256, 0, stream>>>(x1, xx);
    knn_partial<64><<<B_*16*CH_, 256, 0, stream>>>(x1, xx, pV, pI);
    k_merge<<<BN_/256, 256, 0, stream>>>(pV, pI, idxb);
    edgeconv<64,64,4><<<BN_/4, 256, 0, stream>>>(x1, idxb, t2, bn2, x2);
    // stage 3
    k_sqnorm<64><<<BN_/256, 256, 0, stream>>>(x2, xx);
    knn_partial<64><<<B_*16*CH_, 256, 0, stream>>>(x2, xx, pV, pI);
    k_merge<<<BN_/256, 256, 0, stream>>>(pV, pI, idxb);
    edgeconv<64,128,2><<<BN_/2, 256, 0, stream>>>(x2, idxb, t3, bn3, x3);

    k_lin4<<<BN_, 256, 0, stream>>>(x1, x2, x3, l4a, l4b, vb, ub, fmA);
    k_softmax<<<PIX_/4, 256, 0, stream>>>(fmA);

    k_dcnval<<<PIX_*64/256, 256, 0, stream>>>(fmA, d5vw, d5vb, fmV);
    k_dcnsamp<<<PIX_, 128, 0, stream>>>(fmA, fmV, d5ow, d5ob, d5pw, d5pb, bn5, fmB);
    k_dcnval<<<PIX_*64/256, 256, 0, stream>>>(fmB, d6vw, d6vb, fmV);
    k_dcnsamp<<<PIX_, 128, 0, stream>>>(fmB, fmV, d6ow, d6ob, d6pw, d6pb, bn6, fmA);

    k_conv7<<<PIX_, 128, 0, stream>>>(fmA, t7a, t7b, out);
}